// Round 1
// baseline (592.748 us; speedup 1.0000x reference)
//
#include <hip/hip_runtime.h>
#include <hip/hip_bf16.h>

typedef unsigned short u16;
using f32x4  = __attribute__((ext_vector_type(4))) float;
using bf16x8 = __attribute__((ext_vector_type(8))) short;

typedef __attribute__((address_space(1))) const void global_cvoid;
typedef __attribute__((address_space(3))) void lds_void;

__device__ __forceinline__ void async16(const u16* g, u16* l) {
    // direct global->LDS DMA, 16B per lane, LDS dest = wave-uniform base + lane*16
    __builtin_amdgcn_global_load_lds((global_cvoid*)g, (lds_void*)l, 16, 0, 0);
}

__device__ __forceinline__ u16 f2bf(float f) {
    union { float f; unsigned u; } cv; cv.f = f;
    unsigned r = cv.u + 0x7fff + ((cv.u >> 16) & 1);   // RNE
    return (u16)(r >> 16);
}

// ---------------- cast fp32 -> bf16 (vectorized, memory-bound) ----------------
__global__ __launch_bounds__(256) void cast_kernel(const float* __restrict__ src,
                                                   u16* __restrict__ dst, int n4) {
    int i = blockIdx.x * blockDim.x + threadIdx.x;
    int st = gridDim.x * blockDim.x;
    for (; i < n4; i += st) {
        float4 v = ((const float4*)src)[i];
        ushort4 o;
        o.x = f2bf(v.x); o.y = f2bf(v.y); o.z = f2bf(v.z); o.w = f2bf(v.w);
        ((ushort4*)dst)[i] = o;
    }
}

// ---------------- transpose + cast: fp32 [R][C] -> bf16 [C][R] ----------------
__global__ __launch_bounds__(256) void wtrans_kernel(const float* __restrict__ src,
                                                     u16* __restrict__ dst, int R, int C) {
    __shared__ float tile[64][68];           // 68 pad: 16B-aligned rows, conflict-light
    int ct = blockIdx.x, rt = blockIdx.y;
    int t = threadIdx.x;
    int r = t >> 2;
    const float* s = src + (size_t)(rt * 64 + r) * C + ct * 64;
#pragma unroll
    for (int jj = 0; jj < 4; ++jj) {
        int c4 = (t & 3) + jj * 4;
        float4 v = *(const float4*)(s + c4 * 4);
        *(float4*)&tile[r][c4 * 4] = v;
    }
    __syncthreads();
    int od = t >> 2;
    u16* d = dst + (size_t)(ct * 64 + od) * R + rt * 64;
#pragma unroll
    for (int jj = 0; jj < 4; ++jj) {
        int c4 = (t & 3) + jj * 4;
        ushort4 v;
        v.x = f2bf(tile[c4 * 4 + 0][od]);
        v.y = f2bf(tile[c4 * 4 + 1][od]);
        v.z = f2bf(tile[c4 * 4 + 2][od]);
        v.w = f2bf(tile[c4 * 4 + 3][od]);
        *(ushort4*)(d + c4 * 4) = v;
    }
}

// ------------- V transpose (bf16->bf16): per (b,h) [1024][192] -> [192][1024] -------------
__global__ __launch_bounds__(256) void vtrans_kernel(const u16* __restrict__ QKV,
                                                     u16* __restrict__ VT) {
    __shared__ u16 tile[64][72];
    int kt = blockIdx.x, dt = blockIdx.y, bh = blockIdx.z;
    int b = bh >> 4, h = bh & 15;
    int t = threadIdx.x;
    int r = t >> 2;
    const u16* src = QKV + ((size_t)(b * 3072 + 2048 + kt * 64)) * 3072 + h * 192 + dt * 64;
#pragma unroll
    for (int jj = 0; jj < 4; ++jj) {
        int c4 = (t & 3) + jj * 4;
        ushort4 v = *(const ushort4*)(src + (size_t)r * 3072 + c4 * 4);
        *(ushort4*)&tile[r][c4 * 4] = v;
    }
    __syncthreads();
    int od = t >> 2;
    u16* dst = VT + ((size_t)(bh * 192 + dt * 64 + od)) * 1024 + kt * 64;
#pragma unroll
    for (int jj = 0; jj < 4; ++jj) {
        int c4 = (t & 3) + jj * 4;
        ushort4 v;
        v.x = tile[c4 * 4 + 0][od];
        v.y = tile[c4 * 4 + 1][od];
        v.z = tile[c4 * 4 + 2][od];
        v.w = tile[c4 * 4 + 3][od];
        *(ushort4*)(dst + c4 * 4) = v;
    }
}

// ---------------- 128x128 bf16 GEMM, B^T input (m97 structure) ----------------
// C[m][n] = sum_k A[m][k] * BT[n][k];  OUT_F32: fp32 + bias, else bf16
template<bool OUT_F32>
__global__ __launch_bounds__(256, 2)
void gemm_bt_kernel(const u16* __restrict__ A, const u16* __restrict__ BT,
                    void* __restrict__ Cout, const float* __restrict__ bias,
                    int M, int N, int K) {
    __shared__ u16 lA[128 * 64];
    __shared__ u16 lB[128 * 64];
    const int t = threadIdx.x;
    const int w = t >> 6, lane = t & 63;
    const int nbx = N >> 7;
    const int nwg = gridDim.x;
    int bid = blockIdx.x;
    int cpx = nwg >> 3;                       // XCD-aware swizzle (nwg % 8 == 0)
    int swz = (bid & 7) * cpx + (bid >> 3);
    const int bx = swz % nbx;
    const int by = swz / nbx;
    const size_t m0 = (size_t)by * 128, n0 = (size_t)bx * 128;

    const int lr = lane >> 3;                 // staging: row within 8-row chunk
    const int lc = (lane & 7) * 8;            // staging: ushort col
    const int wr = (w >> 1) * 64, wc = (w & 1) * 64;

    f32x4 acc[4][4] = {};

    for (int kk = 0; kk < K; kk += 64) {
        __syncthreads();
#pragma unroll
        for (int i = 0; i < 4; ++i) {
            int rr = (w * 4 + i) * 8 + lr;
            async16(A  + (m0 + rr) * (size_t)K + kk + lc, &lA[(w * 4 + i) * 512]);
            async16(BT + (n0 + rr) * (size_t)K + kk + lc, &lB[(w * 4 + i) * 512]);
        }
        __syncthreads();
#pragma unroll
        for (int ks = 0; ks < 2; ++ks) {
            bf16x8 af[4], bfv[4];
#pragma unroll
            for (int m = 0; m < 4; ++m)
                af[m] = *(const bf16x8*)&lA[(wr + m * 16 + (lane & 15)) * 64 + ks * 32 + (lane >> 4) * 8];
#pragma unroll
            for (int n = 0; n < 4; ++n)
                bfv[n] = *(const bf16x8*)&lB[(wc + n * 16 + (lane & 15)) * 64 + ks * 32 + (lane >> 4) * 8];
#pragma unroll
            for (int m = 0; m < 4; ++m)
#pragma unroll
                for (int n = 0; n < 4; ++n)
                    acc[m][n] = __builtin_amdgcn_mfma_f32_16x16x32_bf16(af[m], bfv[n], acc[m][n], 0, 0, 0);
        }
    }

    const int r0 = (lane >> 4) * 4;
    const int cl = lane & 15;
    if constexpr (OUT_F32) {
        float* C = (float*)Cout;
#pragma unroll
        for (int m = 0; m < 4; ++m) {
            size_t row = m0 + wr + m * 16 + r0;
#pragma unroll
            for (int n = 0; n < 4; ++n) {
                size_t col = n0 + wc + n * 16 + cl;
                float bv = bias[col];
#pragma unroll
                for (int r = 0; r < 4; ++r)
                    C[(row + r) * (size_t)N + col] = acc[m][n][r] + bv;
            }
        }
    } else {
        u16* C = (u16*)Cout;
#pragma unroll
        for (int m = 0; m < 4; ++m) {
            size_t row = m0 + wr + m * 16 + r0;
#pragma unroll
            for (int n = 0; n < 4; ++n) {
                size_t col = n0 + wc + n * 16 + cl;
#pragma unroll
                for (int r = 0; r < 4; ++r)
                    C[(row + r) * (size_t)N + col] = f2bf(acc[m][n][r]);
            }
        }
    }
}

// ---------------- flash attention: per (b,h), q-tile=64 rows, 4 waves x 16 rows ----------------
// Q/K from QKV (rows = tokens, 192 ch per head); V^T pre-transposed [192][1024].
__global__ __launch_bounds__(256, 2)
void attn_kernel(const u16* __restrict__ QKV, const u16* __restrict__ VT,
                 u16* __restrict__ comb) {
    __shared__ u16 lQ[64 * 192];
    __shared__ u16 lK[64 * 192];
    __shared__ u16 lV[192 * 64];
    __shared__ u16 lP[4 * 16 * 64];

    const int t = threadIdx.x, w = t >> 6, lane = t & 63;
    const int qt = blockIdx.x, h = blockIdx.y, b = blockIdx.z;

    const u16* Qg  = QKV + ((size_t)(b * 3072 + qt * 64)) * 3072 + h * 192;
    const u16* Kg  = QKV + ((size_t)(b * 3072 + 1024)) * 3072 + h * 192;
    const u16* VTg = VT + (size_t)(b * 16 + h) * 192 * 1024;

    // stage Q once: 64 rows x 384B = 1536 16B-chunks; row = chunk/24
#pragma unroll
    for (int i = 0; i < 6; ++i) {
        int chunk = i * 256 + t;
        int r = chunk / 24;
        int c = (chunk % 24) * 8;
        async16(Qg + (size_t)r * 3072 + c, &lQ[(i * 256 + w * 64) * 8]);
    }
    __syncthreads();

    bf16x8 aq[6];
#pragma unroll
    for (int cs = 0; cs < 6; ++cs)
        aq[cs] = *(const bf16x8*)&lQ[(w * 16 + (lane & 15)) * 192 + cs * 32 + (lane >> 4) * 8];

    f32x4 acc_o[12] = {};
    float m2[4]  = {-1e30f, -1e30f, -1e30f, -1e30f};
    float lsum[4] = {0.f, 0.f, 0.f, 0.f};
    const float SC = 0.125f * 1.4426950408889634f;  // scale * log2(e), exp2 domain
    u16* lPw = &lP[w * 1024];

    for (int it = 0; it < 16; ++it) {
        __syncthreads();
        // stage K tile [64][192]
#pragma unroll
        for (int i = 0; i < 6; ++i) {
            int chunk = i * 256 + t;
            int r = chunk / 24;
            int c = (chunk % 24) * 8;
            async16(Kg + (size_t)(it * 64 + r) * 3072 + c, &lK[(i * 256 + w * 64) * 8]);
        }
        // stage V^T tile [192][64]
#pragma unroll
        for (int i = 0; i < 6; ++i) {
            int chunk = i * 256 + t;
            int d = chunk >> 3;
            int c = (chunk & 7) * 8;
            async16(VTg + (size_t)d * 1024 + it * 64 + c, &lV[(i * 256 + w * 64) * 8]);
        }
        __syncthreads();

        // S = Q K^T : 4 col-frags x 6 k-slices
        f32x4 s[4] = {};
#pragma unroll
        for (int kf = 0; kf < 4; ++kf)
#pragma unroll
            for (int cs = 0; cs < 6; ++cs) {
                bf16x8 bk = *(const bf16x8*)&lK[(kf * 16 + (lane & 15)) * 192 + cs * 32 + (lane >> 4) * 8];
                s[kf] = __builtin_amdgcn_mfma_f32_16x16x32_bf16(aq[cs], bk, s[kf], 0, 0, 0);
            }
#pragma unroll
        for (int kf = 0; kf < 4; ++kf) s[kf] *= SC;

        // online softmax (rows = (lane>>4)*4+r; 16-lane-group reduce over k cols)
        float fac[4];
#pragma unroll
        for (int r = 0; r < 4; ++r) {
            float mx = fmaxf(fmaxf(s[0][r], s[1][r]), fmaxf(s[2][r], s[3][r]));
#pragma unroll
            for (int msk = 1; msk < 16; msk <<= 1) mx = fmaxf(mx, __shfl_xor(mx, msk));
            float mn = fmaxf(m2[r], mx);
            fac[r] = exp2f(m2[r] - mn);
            m2[r] = mn;
            float rs = 0.f;
#pragma unroll
            for (int kf = 0; kf < 4; ++kf) {
                float p = exp2f(s[kf][r] - mn);
                s[kf][r] = p;
                rs += p;
            }
#pragma unroll
            for (int msk = 1; msk < 16; msk <<= 1) rs += __shfl_xor(rs, msk);
            lsum[r] = lsum[r] * fac[r] + rs;
        }
#pragma unroll
        for (int df = 0; df < 12; ++df)
#pragma unroll
            for (int r = 0; r < 4; ++r) acc_o[df][r] *= fac[r];

        // P -> per-wave LDS (bf16), layout [16 q][64 k]
#pragma unroll
        for (int r = 0; r < 4; ++r)
#pragma unroll
            for (int kf = 0; kf < 4; ++kf)
                lPw[((lane >> 4) * 4 + r) * 64 + kf * 16 + (lane & 15)] = f2bf(s[kf][r]);

        // O += P V : 12 d-frags x 2 k-slices
#pragma unroll
        for (int ks = 0; ks < 2; ++ks) {
            bf16x8 pa = *(const bf16x8*)&lPw[(lane & 15) * 64 + ks * 32 + (lane >> 4) * 8];
#pragma unroll
            for (int df = 0; df < 12; ++df) {
                bf16x8 bv = *(const bf16x8*)&lV[(df * 16 + (lane & 15)) * 64 + ks * 32 + (lane >> 4) * 8];
                acc_o[df] = __builtin_amdgcn_mfma_f32_16x16x32_bf16(pa, bv, acc_o[df], 0, 0, 0);
            }
        }
    }

    u16* dst = comb + ((size_t)(b * 1024 + qt * 64 + w * 16)) * 3072 + h * 192;
#pragma unroll
    for (int df = 0; df < 12; ++df)
#pragma unroll
        for (int r = 0; r < 4; ++r) {
            int q = (lane >> 4) * 4 + r;
            dst[(size_t)q * 3072 + df * 16 + (lane & 15)] = f2bf(acc_o[df][r] / lsum[r]);
        }
}

// ---------------- host ----------------
extern "C" void kernel_launch(void* const* d_in, const int* in_sizes, int n_in,
                              void* d_out, int out_size, void* d_ws, size_t ws_size,
                              hipStream_t stream) {
    const float* X  = (const float*)d_in[0];   // [8,3072,1024]
    const float* W1 = (const float*)d_in[1];   // [1024,3072]
    const float* W2 = (const float*)d_in[2];   // [3072,1024]
    const float* Bb = (const float*)d_in[3];   // [1024]

    char* ws = (char*)d_ws;
    u16* Xb   = (u16*)(ws);                          // 50,331,648 B ; reused as comb
    u16* W1bT = (u16*)(ws + 50331648);               //  6,291,456 B  [3072][1024]
    u16* W2bT = (u16*)(ws + 56623104);               //  6,291,456 B  [1024][3072]
    u16* QKVb = (u16*)(ws + 62914560);               // 150,994,944 B [24576][3072]
    u16* VT   = (u16*)(ws + 213909504);              // 50,331,648 B  [128][192][1024]
    u16* comb = Xb;                                  // [8192][3072]

    // 1. cast X -> bf16
    cast_kernel<<<2048, 256, 0, stream>>>(X, Xb, (8 * 3072 * 1024) / 4);
    // 2-3. transpose-cast weights to B^T layout
    wtrans_kernel<<<dim3(3072 / 64, 1024 / 64), 256, 0, stream>>>(W1, W1bT, 1024, 3072);
    wtrans_kernel<<<dim3(1024 / 64, 3072 / 64), 256, 0, stream>>>(W2, W2bT, 3072, 1024);
    // 4. QKV = Xb @ W1 (bf16 out)   M=24576 N=3072 K=1024
    gemm_bt_kernel<false><<<(24576 / 128) * (3072 / 128), 256, 0, stream>>>(
        Xb, W1bT, QKVb, nullptr, 24576, 3072, 1024);
    // 5. V^T per (b,h)
    vtrans_kernel<<<dim3(16, 3, 128), 256, 0, stream>>>(QKVb, VT);
    // 6. attention -> comb (bf16)
    attn_kernel<<<dim3(16, 16, 8), 256, 0, stream>>>(QKVb, VT, comb);
    // 7. out = comb @ dense_w + b (fp32)   M=8192 N=1024 K=3072
    gemm_bt_kernel<true><<<(8192 / 128) * (1024 / 128), 256, 0, stream>>>(
        comb, W2bT, d_out, Bb, 8192, 1024, 3072);
}